// Round 19
// baseline (70.159 us; speedup 1.0000x reference)
//
#include <hip/hip_runtime.h>
#include <hip/hip_bf16.h>

// BinaryConv: BN(train) -> sign -> 3x3 conv with sign(W).
// Big path (3 dispatches):
//   K1 k_stats_packw : per-channel f64 stats partials (2048 blk) + sign(W)
//                      packed to MFMA B-fragment layout (256 blk), fused.
//   K2 k_packa_i8    : fold partials -> threshold (per-block, deterministic),
//                      binarize x to i8 +/-1 in c32 halo layout aHT.
//   K3 k_conv_mfma v14: N-split of v12 -> 512 blocks (2/CU), N_b=128 outch,
//                      16 waves/CU (4/SIMD) for 2x TLP at UNCHANGED per-CU W
//                      traffic. A resident 52KB LDS; B depth-3 reg prefetch
//                      (p%3 under full unroll); wave = 2 rows x 32 outch
//                      (acc 2xv16i -- no spill); setprio around MFMAs.
// Fallback (small ws): XNOR-popcount path.

#define NIMG 32
#define C    256
#define K    256

typedef int v4i  __attribute__((ext_vector_type(4)));
typedef int v16i __attribute__((ext_vector_type(16)));

#define AHT_IMG 295936   // 8*34*34*32
#define AHT_KB  36992    // 34*34*32
#define AHT_ROW 1088     // 34*32

// ============================ BIG PATH (MFMA) ===============================

// ---- K1: stats partials (blocks 0..2047) + pack W (blocks 2048..2303) ------
__global__ __launch_bounds__(256) void k_stats_packw(
    const float* __restrict__ x, const float* __restrict__ W,
    double2* __restrict__ partials, char* __restrict__ wfrag) {
  int bx = blockIdx.x;
  int tid = threadIdx.x;
  if (bx >= 2048) {                      // ---- pack W ----
    int k = bx - 2048, c = tid;
    const float* src = W + ((size_t)k * 256 + c) * 9;
    char* dst = wfrag + (size_t)(c >> 4) * 4096 + k * 16 + (c & 15);
    #pragma unroll
    for (int t = 0; t < 9; ++t)
      dst[(size_t)t * 65536] = (src[t] > 0.0f) ? (char)1 : (char)-1;
    return;
  }
  int c = bx >> 3, grp = bx & 7;
  double s = 0.0, sq = 0.0;
  #pragma unroll
  for (int ni = 0; ni < 4; ++ni) {
    int n = grp * 4 + ni;
    const float* p = x + (size_t)n * (C * 1024) + (size_t)c * 1024;
    float4 v = ((const float4*)p)[tid];
    s += (double)v.x + (double)v.y + (double)v.z + (double)v.w;
    sq += (double)v.x * v.x + (double)v.y * v.y
        + (double)v.z * v.z + (double)v.w * v.w;
  }
  for (int o = 32; o > 0; o >>= 1) {
    s += __shfl_down(s, o);
    sq += __shfl_down(sq, o);
  }
  __shared__ double ls[4], lq[4];
  if ((tid & 63) == 0) { ls[tid >> 6] = s; lq[tid >> 6] = sq; }
  __syncthreads();
  if (tid == 0) {
    double2 r;
    r.x = ls[0] + ls[1] + ls[2] + ls[3];
    r.y = lq[0] + lq[1] + lq[2] + lq[3];
    partials[c * 8 + grp] = r;
  }
}

// ---- K2: fold partials -> thresholds (in-block) + binarize to c32 halo -----
__global__ __launch_bounds__(256) void k_packa_i8(
    const float* __restrict__ x, const double2* __restrict__ partials,
    const float* __restrict__ gamma, const float* __restrict__ beta,
    char* __restrict__ aHT) {
  __shared__ float lf[32 * 257];
  __shared__ float lthr[256];
  __shared__ unsigned lfl[256];
  int y = blockIdx.x, n = blockIdx.y, tid = threadIdx.x;

  {                                      // ---- threshold fold (c = tid) ----
    double S = 0.0, Q = 0.0;
    #pragma unroll
    for (int g = 0; g < 8; ++g) {        // fixed order -> deterministic
      double2 p = partials[tid * 8 + g];
      S += p.x; Q += p.y;
    }
    const double N = 32768.0;
    double mean = S / N;
    double var = Q / N - mean * mean;
    double rs = 1.0 / sqrt(var + 1e-5);
    double gm = (double)gamma[tid];
    double bt = (double)beta[tid];
    float t;
    unsigned flip;
    if (gm == 0.0) {
      t = (bt > 0.0) ? -3.0e38f : 3.0e38f;
      flip = 0u;
    } else {
      t = (float)(mean - bt / (rs * gm));
      flip = (gm < 0.0) ? 1u : 0u;
    }
    lthr[tid] = t;
    lfl[tid] = flip;
  }

  #pragma unroll
  for (int it = 0; it < 8; ++it) {
    int c = it * 32 + (tid >> 3), q = tid & 7;
    float4 v = *(const float4*)(x + (size_t)n * 262144 + (size_t)c * 1024
                                + y * 32 + q * 4);
    lf[(q * 4 + 0) * 257 + c] = v.x;
    lf[(q * 4 + 1) * 257 + c] = v.y;
    lf[(q * 4 + 2) * 257 + c] = v.z;
    lf[(q * 4 + 3) * 257 + c] = v.w;
  }
  __syncthreads();
  int xl = tid & 31, cb = tid >> 5;      // pixel x, channel-block of 32
  unsigned wds[8];
  #pragma unroll
  for (int g = 0; g < 8; ++g) {
    unsigned wv = 0;
    #pragma unroll
    for (int jj = 0; jj < 4; ++jj) {
      int c = cb * 32 + g * 4 + jj;
      float v = lf[xl * 257 + c];
      unsigned bit = ((v > lthr[c]) ? 1u : 0u) ^ lfl[c];
      unsigned byte = bit ? 0x01u : 0xFFu;   // +1 / -1 as i8
      wv |= byte << (8 * jj);
    }
    wds[g] = wv;
  }
  char* dst = aHT + ((size_t)n * 8 + cb) * AHT_KB
            + (size_t)(y + 1) * AHT_ROW + (size_t)(xl + 1) * 32;
  uint4 u0, u1;
  u0.x = wds[0]; u0.y = wds[1]; u0.z = wds[2]; u0.w = wds[3];
  u1.x = wds[4]; u1.y = wds[5]; u1.z = wds[6]; u1.w = wds[7];
  *(uint4*)dst = u0;
  *((uint4*)dst + 1) = u1;

  // ---- halo zeroing ----
  uint4 z; z.x = 0; z.y = 0; z.z = 0; z.w = 0;
  if (xl < 2) {  // columns x=0 and x=33 of this row (this cb plane)
    char* hz = aHT + ((size_t)n * 8 + cb) * AHT_KB
             + (size_t)(y + 1) * AHT_ROW + (size_t)(xl * 33) * 32;
    *(uint4*)hz = z;
    *((uint4*)hz + 1) = z;
  }
  if (y == 0 || y == 31) {               // rows 0 / 33, all kb, all x
    int row = (y == 0) ? 0 : 33;
    for (int idx = tid; idx < 272; idx += 256) {
      int kb = idx / 34, xx = idx % 34;
      char* hz = aHT + ((size_t)n * 8 + kb) * AHT_KB
               + (size_t)row * AHT_ROW + (size_t)xx * 32;
      *(uint4*)hz = z;
      *((uint4*)hz + 1) = z;
    }
  }
}

// ---- K3: implicit-GEMM conv v14 ---------------------------------------------
// 512 blocks x 512 thr, 2 blocks/CU; lb = (bx%8)*64 + bx/8 (XCD-chunked).
// lb -> n = lb>>4, ys = (lb>>1)&7, kh = lb&1 (outch half 0/1).
// block: M_b = 128 px (4 rows), N_b = 128 outch (kh*128..).
// wave w: rp = w>>2 (row-pair 0..1), nt = w&3 (32-outch tile) -> acc 2xv16i.
// A: 52,224 B resident in LDS, staged once. plane=(kb*6+rl)*2+hs,
//    byte = plane*544 + px*16.
// B: L2 -> registers, 3 sets x 2 frags indexed p%3 under full unroll
//    (no rotation copies, refill after consumption). setprio around MFMAs.
__global__ __launch_bounds__(512, 4) void k_conv_mfma(
    const char* __restrict__ aHT, const char* __restrict__ wfrag,
    float* __restrict__ out) {
  __shared__ uint4 As4[3264];            // 52,224 B
  char* As = (char*)As4;
  int tid = threadIdx.x;
  int lane = tid & 63, w = tid >> 6;
  int rp = w >> 2, nt = w & 3;
  int bx = blockIdx.x;
  int lb = (bx & 7) * 64 + (bx >> 3);    // bijective XCD-chunked swizzle
  int n = lb >> 4, ys = (lb >> 1) & 7, kh = lb & 1;
  int y0 = ys * 4;
  int xl = lane & 31, hi = lane >> 5;

  // ---- stage A resident (once) ----
  {
    const char* aImg = aHT + (size_t)n * AHT_IMG;
    for (int e = tid; e < 3264; e += 512) {
      int px = e % 34;
      int q = e / 34;
      int hs = q & 1;
      int q2 = q >> 1;
      int rl = q2 % 6;
      int kb = q2 / 6;
      const char* g = aImg + (size_t)kb * AHT_KB
                    + (size_t)(y0 + rl) * AHT_ROW + px * 32 + hs * 16;
      *(v4i*)(As + (size_t)e * 16) = *(const v4i*)g;
    }
  }
  __syncthreads();

  // B pointer: this wave's 32-outch tile; stage p at p*16384, kk1 at +8192
  const char* wB = wfrag + hi * 4096 + (kh * 128 + nt * 32 + xl) * 16;
  // A read base: row-pair rp -> rows y0+rp*2+{0,1} -> rl = 1+dy+rp*2+{0,1}
  int aBase = (rp * 2 + 1) * 1088 + hi * 544 + (xl + 1) * 16;

  v16i a0 = {0}, a1 = {0};
  v4i B[3][2];

  #define LOADB(P, S)                                                         \
    { const char* bp_ = wB + (size_t)(P) * 16384;                             \
      B[S][0] = *(const v4i*)(bp_);                                           \
      B[S][1] = *(const v4i*)(bp_ + 8192); }

  LOADB(0, 0);
  LOADB(1, 1);
  LOADB(2, 2);

  #pragma unroll
  for (int p = 0; p < 36; ++p) {
    const int set = p % 3;               // compile-time under full unroll
    int tap = p >> 2, kb0 = (p & 3) * 2;
    int dy = tap / 3 - 1, dx = tap % 3 - 1;
    int ab = aBase + kb0 * 6528 + dy * 1088 + dx * 16;
    v4i Ar0k0 = *(const v4i*)(As + ab);                  // row0 kk0
    v4i Ar1k0 = *(const v4i*)(As + ab + 1088);           // row1 kk0
    v4i Ar0k1 = *(const v4i*)(As + ab + 6528);           // row0 kk1
    v4i Ar1k1 = *(const v4i*)(As + ab + 6528 + 1088);    // row1 kk1
    __builtin_amdgcn_s_setprio(1);
    a0 = __builtin_amdgcn_mfma_i32_32x32x32_i8(Ar0k0, B[set][0], a0, 0, 0, 0);
    a1 = __builtin_amdgcn_mfma_i32_32x32x32_i8(Ar1k0, B[set][0], a1, 0, 0, 0);
    a0 = __builtin_amdgcn_mfma_i32_32x32x32_i8(Ar0k1, B[set][1], a0, 0, 0, 0);
    a1 = __builtin_amdgcn_mfma_i32_32x32x32_i8(Ar1k1, B[set][1], a1, 0, 0, 0);
    __builtin_amdgcn_s_setprio(0);
    if (p < 33) LOADB(p + 3, set);       // refill the set just consumed
  }
  #undef LOADB

  // ---- epilogue: C/D col = lane&31 (outch), row m = (reg&3)+8*(reg>>2)+4*hi
  size_t ob0 = (size_t)n * 262144 + (size_t)(kh * 128 + nt * 32 + xl) * 1024
             + (size_t)(y0 + rp * 2) * 32 + 4 * hi;
  #pragma unroll
  for (int r = 0; r < 2; ++r) {
    v16i av = (r == 0) ? a0 : a1;
    float* obp = out + ob0 + (size_t)r * 32;
    #pragma unroll
    for (int q = 0; q < 4; ++q) {
      float4 f;
      f.x = (float)av[q * 4 + 0];
      f.y = (float)av[q * 4 + 1];
      f.z = (float)av[q * 4 + 2];
      f.w = (float)av[q * 4 + 3];
      *(float4*)(obp + 8 * q) = f;
    }
  }
}

// ========================= FALLBACK PATH (popcount) =========================

__global__ __launch_bounds__(256) void k_stats_part_fb(
    const float* __restrict__ x, double2* __restrict__ partials) {
  int grp = blockIdx.x;
  int c = blockIdx.y;
  int tid = threadIdx.x;
  double s = 0.0, sq = 0.0;
  #pragma unroll
  for (int ni = 0; ni < 4; ++ni) {
    int n = grp * 4 + ni;
    const float* p = x + (size_t)n * (C * 1024) + (size_t)c * 1024;
    float4 v = ((const float4*)p)[tid];
    s += (double)v.x + (double)v.y + (double)v.z + (double)v.w;
    sq += (double)v.x * v.x + (double)v.y * v.y
        + (double)v.z * v.z + (double)v.w * v.w;
  }
  for (int o = 32; o > 0; o >>= 1) {
    s += __shfl_down(s, o);
    sq += __shfl_down(sq, o);
  }
  __shared__ double ls[4], lq[4];
  if ((tid & 63) == 0) { ls[tid >> 6] = s; lq[tid >> 6] = sq; }
  __syncthreads();
  if (tid == 0) {
    double2 r;
    r.x = ls[0] + ls[1] + ls[2] + ls[3];
    r.y = lq[0] + lq[1] + lq[2] + lq[3];
    partials[c * 8 + grp] = r;
  }
}

__global__ __launch_bounds__(256) void k_packw_corr_final(
    const float* __restrict__ W, const double2* __restrict__ partials,
    const float* __restrict__ gamma, const float* __restrict__ beta,
    unsigned* __restrict__ wp, int* __restrict__ corr,
    unsigned* __restrict__ zp, float* __restrict__ t_out,
    unsigned* __restrict__ flip_out) {
  int bk = blockIdx.x;
  int tid = threadIdx.x;
  if (bk == 256) {
    int c = tid;
    double S = 0.0, Q = 0.0;
    #pragma unroll
    for (int g = 0; g < 8; ++g) {
      double2 p = partials[c * 8 + g];
      S += p.x; Q += p.y;
    }
    const double N = 32768.0;
    double mean = S / N;
    double var = Q / N - mean * mean;
    double rs = 1.0 / sqrt(var + 1e-5);
    double g = (double)gamma[c];
    double b = (double)beta[c];
    float t;
    unsigned flip;
    if (g == 0.0) {
      t = (b > 0.0) ? -3.0e38f : 3.0e38f;
      flip = 0u;
    } else {
      t = (float)(mean - b / (rs * g));
      flip = (g < 0.0) ? 1u : 0u;
    }
    t_out[c] = t;
    flip_out[c] = flip;
    return;
  }
  int k = bk;
  __shared__ unsigned lw[72];
  float w[9];
  const float* src = W + (size_t)k * 2304 + (size_t)tid * 9;
  #pragma unroll
  for (int t = 0; t < 9; ++t) w[t] = src[t];
  int lane = tid & 63, wv = tid >> 6;
  #pragma unroll
  for (int t = 0; t < 9; ++t) {
    unsigned long long m = __ballot(w[t] > 0.0f);
    if (lane == 0) {
      lw[t * 8 + 2 * wv] = (unsigned)m;
      lw[t * 8 + 2 * wv + 1] = (unsigned)(m >> 32);
    }
  }
  __syncthreads();
  if (tid < 72) wp[(size_t)k * 72 + tid] = lw[tid];
  if (tid >= 128 && tid < 144) {
    int cls = tid - 128;
    int sum = 0;
    #pragma unroll
    for (int t = 0; t < 9; ++t) {
      int dy = t / 3 - 1, dx = t % 3 - 1;
      bool inv = (((cls & 1) && dx == -1) || ((cls & 2) && dx == 1) ||
                  ((cls & 4) && dy == -1) || ((cls & 8) && dy == 1));
      if (inv) {
        #pragma unroll
        for (int j = 0; j < 8; ++j) sum += __popc(lw[t * 8 + j]);
      }
    }
    corr[k * 16 + cls] = sum;
  }
  if (bk == 0 && tid >= 192 && tid < 200) zp[tid - 192] = 0u;
}

__global__ __launch_bounds__(256) void k_packa_bits(
    const float* __restrict__ x, const float* __restrict__ t,
    const unsigned* __restrict__ flip, unsigned* __restrict__ ap) {
  int n = blockIdx.y;
  int p0 = blockIdx.x * 64;
  int pix = threadIdx.x & 63;
  int q = threadIdx.x >> 6;
  unsigned w0 = 0, w1 = 0;
  const float* xb = x + (size_t)n * (C * 1024) + p0 + pix;
  #pragma unroll
  for (int i = 0; i < 64; ++i) {
    int c = q * 64 + i;
    float tv = t[c];
    unsigned fl = flip[c];
    float v = xb[(size_t)c * 1024];
    unsigned bit = ((v > tv) ? 1u : 0u) ^ fl;
    if (i < 32) w0 |= bit << i;
    else        w1 |= bit << (i - 32);
  }
  uint2 st; st.x = w0; st.y = w1;
  *(uint2*)(ap + ((size_t)n * 1024 + p0 + pix) * 8 + q * 2) = st;
}

__global__ __launch_bounds__(256) void k_conv_pop(
    const unsigned* __restrict__ ap, const unsigned* __restrict__ wp,
    const int* __restrict__ corr, const unsigned* __restrict__ zp,
    float* __restrict__ out) {
  int n = blockIdx.z;
  int ystrip = blockIdx.y;
  int kc = blockIdx.x;
  int tid = threadIdx.x;
  int lane = tid & 63;
  int wave = tid >> 6;
  int y = ystrip * 8 + wave * 2 + (lane >> 5);
  int xx = lane & 31;
  int cls = (xx == 0 ? 1 : 0) | (xx == 31 ? 2 : 0) |
            (y == 0 ? 4 : 0) | (y == 31 ? 8 : 0);
  uint4 a0[9], a1[9];
  int nv = 0;
  const uint4* zp4 = (const uint4*)zp;
  #pragma unroll
  for (int t = 0; t < 9; ++t) {
    int dy = t / 3 - 1, dx = t % 3 - 1;
    int cy = y + dy, cx = xx + dx;
    bool valid = (cy >= 0) & (cy < 32) & (cx >= 0) & (cx < 32);
    nv += valid ? 1 : 0;
    const uint4* pa = valid
        ? (const uint4*)(ap + (((size_t)n * 32 + cy) * 32 + cx) * 8)
        : zp4;
    a0[t] = pa[0];
    a1[t] = pa[1];
  }
  int bias = nv << 8;
  float* ob = out + (size_t)n * (K * 1024) + (size_t)y * 32 + xx;
  for (int kk = 0; kk < 16; ++kk) {
    int k = kc * 16 + kk;
    const uint4* wq = (const uint4*)(wp + (size_t)k * 72);
    int s0 = 0, s1 = 0, s2 = 0, s3 = 0, s4 = 0, s5 = 0, s6 = 0, s7 = 0;
    #pragma unroll
    for (int t = 0; t < 9; ++t) {
      uint4 wa = wq[t * 2];
      uint4 wb = wq[t * 2 + 1];
      s0 += __popc(a0[t].x ^ wa.x);
      s1 += __popc(a0[t].y ^ wa.y);
      s2 += __popc(a0[t].z ^ wa.z);
      s3 += __popc(a0[t].w ^ wa.w);
      s4 += __popc(a1[t].x ^ wb.x);
      s5 += __popc(a1[t].y ^ wb.y);
      s6 += __popc(a1[t].z ^ wb.z);
      s7 += __popc(a1[t].w ^ wb.w);
    }
    int S = ((s0 + s1) + (s2 + s3)) + ((s4 + s5) + (s6 + s7));
    int tot = corr[(k << 4) + cls] - S;
    ob[(size_t)k * 1024] = (float)(bias + 2 * tot);
  }
}

// ============================================================================

extern "C" void kernel_launch(void* const* d_in, const int* in_sizes, int n_in,
                              void* d_out, int out_size, void* d_ws, size_t ws_size,
                              hipStream_t stream) {
  const float* x = (const float*)d_in[0];
  const float* gamma = (const float*)d_in[1];
  const float* beta = (const float*)d_in[2];
  const float* W = (const float*)d_in[3];
  float* out = (float*)d_out;
  char* ws = (char*)d_ws;

  const size_t NEED = 655360 + (size_t)NIMG * AHT_IMG;  // ~10.1 MB
  if (ws_size >= NEED) {
    double2* partials = (double2*)(ws + 4096);   // 32 KB
    char* wfrag = ws + 36864;                    // 589,824 B
    char* aHT = ws + 655360;                     // 9,469,952 B

    k_stats_packw<<<2304, 256, 0, stream>>>(x, W, partials, wfrag);
    k_packa_i8<<<dim3(32, 32), 256, 0, stream>>>(x, partials, gamma, beta, aHT);
    k_conv_mfma<<<512, 512, 0, stream>>>(aHT, wfrag, out);
  } else {
    float* t = (float*)ws;
    unsigned* flip = (unsigned*)(ws + 1024);
    unsigned* wp = (unsigned*)(ws + 4096);
    unsigned* zp = (unsigned*)(ws + 77824);
    int* corr = (int*)(ws + 78336);
    double2* partials = (double2*)(ws + 98304);
    unsigned* ap = (unsigned*)(ws + 131072);

    k_stats_part_fb<<<dim3(8, 256), 256, 0, stream>>>(x, partials);
    k_packw_corr_final<<<257, 256, 0, stream>>>(W, partials, gamma, beta,
                                                wp, corr, zp, t, flip);
    k_packa_bits<<<dim3(16, 32), 256, 0, stream>>>(x, t, flip, ap);
    k_conv_pop<<<dim3(16, 4, 32), 256, 0, stream>>>(ap, wp, corr, zp, out);
  }
}

// Round 20
// 48.163 us; speedup vs baseline: 1.4567x; 1.4567x over previous
//
#include <hip/hip_runtime.h>
#include <hip/hip_bf16.h>

// BinaryConv: BN(train) -> sign -> 3x3 conv with sign(W).
// Big path (3 dispatches):
//   K1 k_stats_packw : per-channel f64 stats partials (2048 blk) + sign(W)
//                      packed to MFMA B-fragment layout (256 blk), fused.
//   K2 k_packa_i8    : fold partials -> threshold (per-block, deterministic),
//                      binarize x to i8 +/-1 in c32 halo layout aHT.
//   K3 k_conv_mfma v12: A resident 52KB LDS (staged once), B direct L2 with
//                      depth-3 reg prefetch (3 sets, p%3 under full unroll,
//                      no rotation copies) + s_setprio around MFMAs.
//                      BEST MEASURED: 48.19 us, absmax 0 (rounds 16/18).
//                      [v13 M128xN32 and v14 N-split/launch_bounds REVERTED:
//                       both spilled registers -> WRITE_SIZE 122-183MB.]
// Fallback (small ws): XNOR-popcount path.

#define NIMG 32
#define C    256
#define K    256

typedef int v4i  __attribute__((ext_vector_type(4)));
typedef int v16i __attribute__((ext_vector_type(16)));

#define AHT_IMG 295936   // 8*34*34*32
#define AHT_KB  36992    // 34*34*32
#define AHT_ROW 1088     // 34*32

// ============================ BIG PATH (MFMA) ===============================

// ---- K1: stats partials (blocks 0..2047) + pack W (blocks 2048..2303) ------
__global__ __launch_bounds__(256) void k_stats_packw(
    const float* __restrict__ x, const float* __restrict__ W,
    double2* __restrict__ partials, char* __restrict__ wfrag) {
  int bx = blockIdx.x;
  int tid = threadIdx.x;
  if (bx >= 2048) {                      // ---- pack W ----
    int k = bx - 2048, c = tid;
    const float* src = W + ((size_t)k * 256 + c) * 9;
    char* dst = wfrag + (size_t)(c >> 4) * 4096 + k * 16 + (c & 15);
    #pragma unroll
    for (int t = 0; t < 9; ++t)
      dst[(size_t)t * 65536] = (src[t] > 0.0f) ? (char)1 : (char)-1;
    return;
  }
  int c = bx >> 3, grp = bx & 7;
  double s = 0.0, sq = 0.0;
  #pragma unroll
  for (int ni = 0; ni < 4; ++ni) {
    int n = grp * 4 + ni;
    const float* p = x + (size_t)n * (C * 1024) + (size_t)c * 1024;
    float4 v = ((const float4*)p)[tid];
    s += (double)v.x + (double)v.y + (double)v.z + (double)v.w;
    sq += (double)v.x * v.x + (double)v.y * v.y
        + (double)v.z * v.z + (double)v.w * v.w;
  }
  for (int o = 32; o > 0; o >>= 1) {
    s += __shfl_down(s, o);
    sq += __shfl_down(sq, o);
  }
  __shared__ double ls[4], lq[4];
  if ((tid & 63) == 0) { ls[tid >> 6] = s; lq[tid >> 6] = sq; }
  __syncthreads();
  if (tid == 0) {
    double2 r;
    r.x = ls[0] + ls[1] + ls[2] + ls[3];
    r.y = lq[0] + lq[1] + lq[2] + lq[3];
    partials[c * 8 + grp] = r;
  }
}

// ---- K2: fold partials -> thresholds (in-block) + binarize to c32 halo -----
__global__ __launch_bounds__(256) void k_packa_i8(
    const float* __restrict__ x, const double2* __restrict__ partials,
    const float* __restrict__ gamma, const float* __restrict__ beta,
    char* __restrict__ aHT) {
  __shared__ float lf[32 * 257];
  __shared__ float lthr[256];
  __shared__ unsigned lfl[256];
  int y = blockIdx.x, n = blockIdx.y, tid = threadIdx.x;

  {                                      // ---- threshold fold (c = tid) ----
    double S = 0.0, Q = 0.0;
    #pragma unroll
    for (int g = 0; g < 8; ++g) {        // fixed order -> deterministic
      double2 p = partials[tid * 8 + g];
      S += p.x; Q += p.y;
    }
    const double N = 32768.0;
    double mean = S / N;
    double var = Q / N - mean * mean;
    double rs = 1.0 / sqrt(var + 1e-5);
    double gm = (double)gamma[tid];
    double bt = (double)beta[tid];
    float t;
    unsigned flip;
    if (gm == 0.0) {
      t = (bt > 0.0) ? -3.0e38f : 3.0e38f;
      flip = 0u;
    } else {
      t = (float)(mean - bt / (rs * gm));
      flip = (gm < 0.0) ? 1u : 0u;
    }
    lthr[tid] = t;
    lfl[tid] = flip;
  }

  #pragma unroll
  for (int it = 0; it < 8; ++it) {
    int c = it * 32 + (tid >> 3), q = tid & 7;
    float4 v = *(const float4*)(x + (size_t)n * 262144 + (size_t)c * 1024
                                + y * 32 + q * 4);
    lf[(q * 4 + 0) * 257 + c] = v.x;
    lf[(q * 4 + 1) * 257 + c] = v.y;
    lf[(q * 4 + 2) * 257 + c] = v.z;
    lf[(q * 4 + 3) * 257 + c] = v.w;
  }
  __syncthreads();
  int xl = tid & 31, cb = tid >> 5;      // pixel x, channel-block of 32
  unsigned wds[8];
  #pragma unroll
  for (int g = 0; g < 8; ++g) {
    unsigned wv = 0;
    #pragma unroll
    for (int jj = 0; jj < 4; ++jj) {
      int c = cb * 32 + g * 4 + jj;
      float v = lf[xl * 257 + c];
      unsigned bit = ((v > lthr[c]) ? 1u : 0u) ^ lfl[c];
      unsigned byte = bit ? 0x01u : 0xFFu;   // +1 / -1 as i8
      wv |= byte << (8 * jj);
    }
    wds[g] = wv;
  }
  char* dst = aHT + ((size_t)n * 8 + cb) * AHT_KB
            + (size_t)(y + 1) * AHT_ROW + (size_t)(xl + 1) * 32;
  uint4 u0, u1;
  u0.x = wds[0]; u0.y = wds[1]; u0.z = wds[2]; u0.w = wds[3];
  u1.x = wds[4]; u1.y = wds[5]; u1.z = wds[6]; u1.w = wds[7];
  *(uint4*)dst = u0;
  *((uint4*)dst + 1) = u1;

  // ---- halo zeroing ----
  uint4 z; z.x = 0; z.y = 0; z.z = 0; z.w = 0;
  if (xl < 2) {  // columns x=0 and x=33 of this row (this cb plane)
    char* hz = aHT + ((size_t)n * 8 + cb) * AHT_KB
             + (size_t)(y + 1) * AHT_ROW + (size_t)(xl * 33) * 32;
    *(uint4*)hz = z;
    *((uint4*)hz + 1) = z;
  }
  if (y == 0 || y == 31) {               // rows 0 / 33, all kb, all x
    int row = (y == 0) ? 0 : 33;
    for (int idx = tid; idx < 272; idx += 256) {
      int kb = idx / 34, xx = idx % 34;
      char* hz = aHT + ((size_t)n * 8 + kb) * AHT_KB
               + (size_t)row * AHT_ROW + (size_t)xx * 32;
      *(uint4*)hz = z;
      *((uint4*)hz + 1) = z;
    }
  }
}

// ---- K3: implicit-GEMM conv v12 ---------------------------------------------
// 256 blocks x 512 thr; lb = (bx%8)*32 + bx/8 (XCD-chunked, bijective).
// block: (n, ystrip of 4 rows); M_b = 128 px, N = 256 outch.
// wave w: mb = w>>2 (row-pair), nh = w&3 (N-quarter of 64).
// A: 52,224 B resident in LDS, staged once (all 9 taps reuse it).
//    plane = (kb*6+rl)*2+hs; byte = plane*544 + px*16.
// B: L2 -> registers, 3 sets indexed p%3 (compile-time under full unroll),
//    refill issued AFTER consumption (true depth-3, no rotation copies).
// s_setprio(1) around each MFMA cluster (T5).
__global__ __launch_bounds__(512) void k_conv_mfma(
    const char* __restrict__ aHT, const char* __restrict__ wfrag,
    float* __restrict__ out) {
  __shared__ uint4 As4[3264];            // 52,224 B
  char* As = (char*)As4;
  int tid = threadIdx.x;
  int lane = tid & 63, w = tid >> 6;
  int nh = w & 3, mb = w >> 2;
  int bx = blockIdx.x;
  int lb = (bx & 7) * 32 + (bx >> 3);    // bijective XCD-chunked swizzle
  int n = lb >> 3, ys = lb & 7;
  int y0 = ys * 4;
  int yw = y0 + mb * 2;                  // this wave's first output row
  int xl = lane & 31, hi = lane >> 5;

  // ---- stage A resident (once) ----
  {
    const char* aImg = aHT + (size_t)n * AHT_IMG;
    for (int e = tid; e < 3264; e += 512) {
      int px = e % 34;
      int q = e / 34;
      int hs = q & 1;
      int q2 = q >> 1;
      int rl = q2 % 6;
      int kb = q2 / 6;
      const char* g = aImg + (size_t)kb * AHT_KB
                    + (size_t)(y0 + rl) * AHT_ROW + px * 32 + hs * 16;
      *(v4i*)(As + (size_t)e * 16) = *(const v4i*)g;
    }
  }
  __syncthreads();

  // B pointer (fragment layout): stage p covers kk = 2p, 2p+1 at p*16384
  const char* wB = wfrag + hi * 4096 + (nh * 64 + xl) * 16;
  // A read addr = aBase + kb0*6528 + dy*1088 + dx*16 (+1088 rr, +6528 kk1)
  int aBase = (mb * 2 + 1) * 1088 + hi * 544 + (xl + 1) * 16;

  v16i a00 = {0}, a01 = {0}, a10 = {0}, a11 = {0};
  v4i B[3][4];

  #define LOADB(P, S)                                                         \
    { const char* bp_ = wB + (size_t)(P) * 16384;                             \
      B[S][0] = *(const v4i*)(bp_);                                           \
      B[S][1] = *(const v4i*)(bp_ + 512);                                     \
      B[S][2] = *(const v4i*)(bp_ + 8192);                                    \
      B[S][3] = *(const v4i*)(bp_ + 8704); }

  LOADB(0, 0);
  LOADB(1, 1);
  LOADB(2, 2);

  #pragma unroll
  for (int p = 0; p < 36; ++p) {
    const int set = p % 3;               // compile-time under full unroll
    int tap = p >> 2, kb0 = (p & 3) * 2;
    int dy = tap / 3 - 1, dx = tap % 3 - 1;
    int ab = aBase + kb0 * 6528 + dy * 1088 + dx * 16;
    v4i Ar0k0 = *(const v4i*)(As + ab);                  // rr0 kk0
    v4i Ar1k0 = *(const v4i*)(As + ab + 1088);           // rr1 kk0
    v4i Ar0k1 = *(const v4i*)(As + ab + 6528);           // rr0 kk1
    v4i Ar1k1 = *(const v4i*)(As + ab + 6528 + 1088);    // rr1 kk1
    __builtin_amdgcn_s_setprio(1);
    a00 = __builtin_amdgcn_mfma_i32_32x32x32_i8(Ar0k0, B[set][0], a00, 0, 0, 0);
    a01 = __builtin_amdgcn_mfma_i32_32x32x32_i8(Ar0k0, B[set][1], a01, 0, 0, 0);
    a10 = __builtin_amdgcn_mfma_i32_32x32x32_i8(Ar1k0, B[set][0], a10, 0, 0, 0);
    a11 = __builtin_amdgcn_mfma_i32_32x32x32_i8(Ar1k0, B[set][1], a11, 0, 0, 0);
    a00 = __builtin_amdgcn_mfma_i32_32x32x32_i8(Ar0k1, B[set][2], a00, 0, 0, 0);
    a01 = __builtin_amdgcn_mfma_i32_32x32x32_i8(Ar0k1, B[set][3], a01, 0, 0, 0);
    a10 = __builtin_amdgcn_mfma_i32_32x32x32_i8(Ar1k1, B[set][2], a10, 0, 0, 0);
    a11 = __builtin_amdgcn_mfma_i32_32x32x32_i8(Ar1k1, B[set][3], a11, 0, 0, 0);
    __builtin_amdgcn_s_setprio(0);
    if (p < 33) LOADB(p + 3, set);       // refill the set just consumed
  }
  #undef LOADB

  // ---- epilogue: C/D col = lane&31 (outch), row m = (reg&3)+8*(reg>>2)+4*hi
  size_t ob0 = (size_t)n * 262144 + (size_t)(nh * 64 + xl) * 1024
             + (size_t)yw * 32 + 4 * hi;
  #pragma unroll
  for (int r = 0; r < 2; ++r) {
    #pragma unroll
    for (int nb = 0; nb < 2; ++nb) {
      v16i av = (r == 0) ? (nb == 0 ? a00 : a01) : (nb == 0 ? a10 : a11);
      float* obp = out + ob0 + (size_t)nb * 32768 + r * 32;
      #pragma unroll
      for (int q = 0; q < 4; ++q) {
        float4 f;
        f.x = (float)av[q * 4 + 0];
        f.y = (float)av[q * 4 + 1];
        f.z = (float)av[q * 4 + 2];
        f.w = (float)av[q * 4 + 3];
        *(float4*)(obp + 8 * q) = f;
      }
    }
  }
}

// ========================= FALLBACK PATH (popcount) =========================

__global__ __launch_bounds__(256) void k_stats_part_fb(
    const float* __restrict__ x, double2* __restrict__ partials) {
  int grp = blockIdx.x;
  int c = blockIdx.y;
  int tid = threadIdx.x;
  double s = 0.0, sq = 0.0;
  #pragma unroll
  for (int ni = 0; ni < 4; ++ni) {
    int n = grp * 4 + ni;
    const float* p = x + (size_t)n * (C * 1024) + (size_t)c * 1024;
    float4 v = ((const float4*)p)[tid];
    s += (double)v.x + (double)v.y + (double)v.z + (double)v.w;
    sq += (double)v.x * v.x + (double)v.y * v.y
        + (double)v.z * v.z + (double)v.w * v.w;
  }
  for (int o = 32; o > 0; o >>= 1) {
    s += __shfl_down(s, o);
    sq += __shfl_down(sq, o);
  }
  __shared__ double ls[4], lq[4];
  if ((tid & 63) == 0) { ls[tid >> 6] = s; lq[tid >> 6] = sq; }
  __syncthreads();
  if (tid == 0) {
    double2 r;
    r.x = ls[0] + ls[1] + ls[2] + ls[3];
    r.y = lq[0] + lq[1] + lq[2] + lq[3];
    partials[c * 8 + grp] = r;
  }
}

__global__ __launch_bounds__(256) void k_packw_corr_final(
    const float* __restrict__ W, const double2* __restrict__ partials,
    const float* __restrict__ gamma, const float* __restrict__ beta,
    unsigned* __restrict__ wp, int* __restrict__ corr,
    unsigned* __restrict__ zp, float* __restrict__ t_out,
    unsigned* __restrict__ flip_out) {
  int bk = blockIdx.x;
  int tid = threadIdx.x;
  if (bk == 256) {
    int c = tid;
    double S = 0.0, Q = 0.0;
    #pragma unroll
    for (int g = 0; g < 8; ++g) {
      double2 p = partials[c * 8 + g];
      S += p.x; Q += p.y;
    }
    const double N = 32768.0;
    double mean = S / N;
    double var = Q / N - mean * mean;
    double rs = 1.0 / sqrt(var + 1e-5);
    double g = (double)gamma[c];
    double b = (double)beta[c];
    float t;
    unsigned flip;
    if (g == 0.0) {
      t = (b > 0.0) ? -3.0e38f : 3.0e38f;
      flip = 0u;
    } else {
      t = (float)(mean - b / (rs * g));
      flip = (g < 0.0) ? 1u : 0u;
    }
    t_out[c] = t;
    flip_out[c] = flip;
    return;
  }
  int k = bk;
  __shared__ unsigned lw[72];
  float w[9];
  const float* src = W + (size_t)k * 2304 + (size_t)tid * 9;
  #pragma unroll
  for (int t = 0; t < 9; ++t) w[t] = src[t];
  int lane = tid & 63, wv = tid >> 6;
  #pragma unroll
  for (int t = 0; t < 9; ++t) {
    unsigned long long m = __ballot(w[t] > 0.0f);
    if (lane == 0) {
      lw[t * 8 + 2 * wv] = (unsigned)m;
      lw[t * 8 + 2 * wv + 1] = (unsigned)(m >> 32);
    }
  }
  __syncthreads();
  if (tid < 72) wp[(size_t)k * 72 + tid] = lw[tid];
  if (tid >= 128 && tid < 144) {
    int cls = tid - 128;
    int sum = 0;
    #pragma unroll
    for (int t = 0; t < 9; ++t) {
      int dy = t / 3 - 1, dx = t % 3 - 1;
      bool inv = (((cls & 1) && dx == -1) || ((cls & 2) && dx == 1) ||
                  ((cls & 4) && dy == -1) || ((cls & 8) && dy == 1));
      if (inv) {
        #pragma unroll
        for (int j = 0; j < 8; ++j) sum += __popc(lw[t * 8 + j]);
      }
    }
    corr[k * 16 + cls] = sum;
  }
  if (bk == 0 && tid >= 192 && tid < 200) zp[tid - 192] = 0u;
}

__global__ __launch_bounds__(256) void k_packa_bits(
    const float* __restrict__ x, const float* __restrict__ t,
    const unsigned* __restrict__ flip, unsigned* __restrict__ ap) {
  int n = blockIdx.y;
  int p0 = blockIdx.x * 64;
  int pix = threadIdx.x & 63;
  int q = threadIdx.x >> 6;
  unsigned w0 = 0, w1 = 0;
  const float* xb = x + (size_t)n * (C * 1024) + p0 + pix;
  #pragma unroll
  for (int i = 0; i < 64; ++i) {
    int c = q * 64 + i;
    float tv = t[c];
    unsigned fl = flip[c];
    float v = xb[(size_t)c * 1024];
    unsigned bit = ((v > tv) ? 1u : 0u) ^ fl;
    if (i < 32) w0 |= bit << i;
    else        w1 |= bit << (i - 32);
  }
  uint2 st; st.x = w0; st.y = w1;
  *(uint2*)(ap + ((size_t)n * 1024 + p0 + pix) * 8 + q * 2) = st;
}

__global__ __launch_bounds__(256) void k_conv_pop(
    const unsigned* __restrict__ ap, const unsigned* __restrict__ wp,
    const int* __restrict__ corr, const unsigned* __restrict__ zp,
    float* __restrict__ out) {
  int n = blockIdx.z;
  int ystrip = blockIdx.y;
  int kc = blockIdx.x;
  int tid = threadIdx.x;
  int lane = tid & 63;
  int wave = tid >> 6;
  int y = ystrip * 8 + wave * 2 + (lane >> 5);
  int xx = lane & 31;
  int cls = (xx == 0 ? 1 : 0) | (xx == 31 ? 2 : 0) |
            (y == 0 ? 4 : 0) | (y == 31 ? 8 : 0);
  uint4 a0[9], a1[9];
  int nv = 0;
  const uint4* zp4 = (const uint4*)zp;
  #pragma unroll
  for (int t = 0; t < 9; ++t) {
    int dy = t / 3 - 1, dx = t % 3 - 1;
    int cy = y + dy, cx = xx + dx;
    bool valid = (cy >= 0) & (cy < 32) & (cx >= 0) & (cx < 32);
    nv += valid ? 1 : 0;
    const uint4* pa = valid
        ? (const uint4*)(ap + (((size_t)n * 32 + cy) * 32 + cx) * 8)
        : zp4;
    a0[t] = pa[0];
    a1[t] = pa[1];
  }
  int bias = nv << 8;
  float* ob = out + (size_t)n * (K * 1024) + (size_t)y * 32 + xx;
  for (int kk = 0; kk < 16; ++kk) {
    int k = kc * 16 + kk;
    const uint4* wq = (const uint4*)(wp + (size_t)k * 72);
    int s0 = 0, s1 = 0, s2 = 0, s3 = 0, s4 = 0, s5 = 0, s6 = 0, s7 = 0;
    #pragma unroll
    for (int t = 0; t < 9; ++t) {
      uint4 wa = wq[t * 2];
      uint4 wb = wq[t * 2 + 1];
      s0 += __popc(a0[t].x ^ wa.x);
      s1 += __popc(a0[t].y ^ wa.y);
      s2 += __popc(a0[t].z ^ wa.z);
      s3 += __popc(a0[t].w ^ wa.w);
      s4 += __popc(a1[t].x ^ wb.x);
      s5 += __popc(a1[t].y ^ wb.y);
      s6 += __popc(a1[t].z ^ wb.z);
      s7 += __popc(a1[t].w ^ wb.w);
    }
    int S = ((s0 + s1) + (s2 + s3)) + ((s4 + s5) + (s6 + s7));
    int tot = corr[(k << 4) + cls] - S;
    ob[(size_t)k * 1024] = (float)(bias + 2 * tot);
  }
}

// ============================================================================

extern "C" void kernel_launch(void* const* d_in, const int* in_sizes, int n_in,
                              void* d_out, int out_size, void* d_ws, size_t ws_size,
                              hipStream_t stream) {
  const float* x = (const float*)d_in[0];
  const float* gamma = (const float*)d_in[1];
  const float* beta = (const float*)d_in[2];
  const float* W = (const float*)d_in[3];
  float* out = (float*)d_out;
  char* ws = (char*)d_ws;

  const size_t NEED = 655360 + (size_t)NIMG * AHT_IMG;  // ~10.1 MB
  if (ws_size >= NEED) {
    double2* partials = (double2*)(ws + 4096);   // 32 KB
    char* wfrag = ws + 36864;                    // 589,824 B
    char* aHT = ws + 655360;                     // 9,469,952 B

    k_stats_packw<<<2304, 256, 0, stream>>>(x, W, partials, wfrag);
    k_packa_i8<<<dim3(32, 32), 256, 0, stream>>>(x, partials, gamma, beta, aHT);
    k_conv_mfma<<<256, 512, 0, stream>>>(aHT, wfrag, out);
  } else {
    float* t = (float*)ws;
    unsigned* flip = (unsigned*)(ws + 1024);
    unsigned* wp = (unsigned*)(ws + 4096);
    unsigned* zp = (unsigned*)(ws + 77824);
    int* corr = (int*)(ws + 78336);
    double2* partials = (double2*)(ws + 98304);
    unsigned* ap = (unsigned*)(ws + 131072);

    k_stats_part_fb<<<dim3(8, 256), 256, 0, stream>>>(x, partials);
    k_packw_corr_final<<<257, 256, 0, stream>>>(W, partials, gamma, beta,
                                                wp, corr, zp, t, flip);
    k_packa_bits<<<dim3(16, 32), 256, 0, stream>>>(x, t, flip, ap);
    k_conv_pop<<<dim3(16, 4, 32), 256, 0, stream>>>(ap, wp, corr, zp, out);
  }
}